// Round 9
// baseline (451.964 us; speedup 1.0000x reference)
//
#include <hip/hip_runtime.h>

// HIGNN, round 9. Two-phase bucketed scatter + packed-fp16 dot2 MLP.
// R8 post-mortem: p1 = 168us with VALUBusy 32% -> ~68% stalled; per-wave
// busy ~13% at ~11 waves/CU. Diagnosis: dependent idx->x4 gather chains at
// L3 latency (record writes wash L2) + no cross-tile overlap.
// R9: (a) software-pipeline pass B (prefetch tile t+1 regs during tile t MLP),
//     (b) nontemporal stores for records / nt loads for read-once streams
//         (keep 1.6MB x4 table L2-resident), (c) SPAN 4096, KPT=2.

constexpr int HIDDEN = 64;
constexpr int NB_MAX = 256;      // LDS histogram bins (>= nbuckets)
constexpr int NPB_SHIFT = 9;     // 512 nodes per bucket
constexpr int NPB = 1 << NPB_SHIFT;
constexpr int SSPLIT = 8;        // p2 sub-blocks per bucket
constexpr int TILE_F = NPB * 3;  // floats per bucket tile (1536)
constexpr int TILE_F4 = TILE_F / 4;
constexpr int NET_SLOT = 1024;   // dwords per packed-net slot

typedef _Float16 h2_t __attribute__((ext_vector_type(2)));
typedef float f32x4 __attribute__((ext_vector_type(4)));

__device__ __forceinline__ unsigned packh2(float a, float b) {
    auto h = __builtin_amdgcn_cvt_pkrtz(a, b);   // __fp16 ext_vector(2)
    return __builtin_bit_cast(unsigned, h);
}
__device__ __forceinline__ float fdot2u(unsigned a, unsigned b, float c) {
    h2_t ha = __builtin_bit_cast(h2_t, a);
    h2_t hb = __builtin_bit_cast(h2_t, b);
#if __has_builtin(__builtin_amdgcn_fdot2)
    return __builtin_amdgcn_fdot2(ha, hb, c, false);
#else
    return fmaf((float)ha.x, (float)hb.x, fmaf((float)ha.y, (float)hb.y, c));
#endif
}

// Packed net slot layout (dword indices within NET_SLOT):
// [0..191]   W1 packed u32. DIN3: [hh] = (W1[0][hh],W1[1][hh]).
//            DIN6: [hh*3+r] = (W1[2r][hh],W1[2r+1][hh]).
// [192..255] b1 f32
// [256..543] W2 packed u32: [256+hh2*9+i] = (W2[2hh2][i],W2[2hh2+1][i])
// [544..552] b2 f32
// [560..623] w1c f32 (DIN3 third-row weight per hh)

// ---------------- Setup: pack 3 nets + zero gcount + pad x ----------------
__global__ __launch_bounds__(256) void setup_kernel(
    const float* __restrict__ x, int n_nodes, float4* __restrict__ x4,
    int* __restrict__ gcount,
    const float* __restrict__ W1_2b, const float* __restrict__ b1_2b,
    const float* __restrict__ W2_2b, const float* __restrict__ b2_2b,
    const float* __restrict__ W1_s,  const float* __restrict__ b1_s,
    const float* __restrict__ W2_s,  const float* __restrict__ b2_s,
    const float* __restrict__ W1_3b, const float* __restrict__ b1_3b,
    const float* __restrict__ W2_3b, const float* __restrict__ b2_3b,
    unsigned* __restrict__ nets)
{
    const int blk = blockIdx.x;
    const int tid = threadIdx.x;
    if (blk < 3) {
        const float *W1, *b1, *W2, *b2; int din;
        if (blk == 0) { W1 = W1_2b; b1 = b1_2b; W2 = W2_2b; b2 = b2_2b; din = 3; }
        else if (blk == 1) { W1 = W1_s; b1 = b1_s; W2 = W2_s; b2 = b2_s; din = 3; }
        else { W1 = W1_3b; b1 = b1_3b; W2 = W2_3b; b2 = b2_3b; din = 6; }
        unsigned* slot = nets + blk * NET_SLOT;
        float* slotf = (float*)slot;
        if (tid < 64) {
            int hh = tid;
            if (din == 3) {
                slot[hh] = packh2(W1[0 * HIDDEN + hh], W1[1 * HIDDEN + hh]);
                slotf[560 + hh] = W1[2 * HIDDEN + hh];
            } else {
                #pragma unroll
                for (int r = 0; r < 3; ++r)
                    slot[hh * 3 + r] =
                        packh2(W1[(2 * r) * HIDDEN + hh], W1[(2 * r + 1) * HIDDEN + hh]);
            }
            slotf[192 + hh] = b1[hh];
        }
        for (int t = tid; t < 288; t += 256) {
            int hh2 = t / 9, i = t - hh2 * 9;
            slot[256 + t] = packh2(W2[(2 * hh2) * 9 + i], W2[(2 * hh2 + 1) * 9 + i]);
        }
        if (tid < 9) slotf[544 + tid] = b2[tid];
        if (blk == 0) gcount[tid] = 0;   // tid < 256 == NB_MAX
    } else {
        int i = (blk - 3) * 256 + tid;
        if (i < n_nodes)
            x4[i] = make_float4(x[3 * i], x[3 * i + 1], x[3 * i + 2], 0.0f);
    }
}

// ---------------- Phase 1: all 3 edge sets, MLP + bucket append ----------------
__global__ __launch_bounds__(256) void p1_edge_kernel(
    const float4* __restrict__ x4,
    const int* __restrict__ e0, long long E0, const float* __restrict__ at0,
    const int* __restrict__ e1, long long E1, const float* __restrict__ at1,
    const int* __restrict__ e2, long long E2, const float* __restrict__ at2,
    int g0, int g1,
    const unsigned* __restrict__ nets,
    float4* __restrict__ records, int* __restrict__ gcount, int cap)
{
    constexpr int BLK = 256;
    constexpr int KPT = 2;
    constexpr int TILE = BLK * KPT;   // 512 edges per tile

    __shared__ int s_hist[NB_MAX];
    __shared__ int s_base[NB_MAX];
    __shared__ int s_rank[NB_MAX];

    const f32x4* xv = reinterpret_cast<const f32x4*>(x4);

    // block-uniform set select (set index == net index)
    const int blk = blockIdx.x;
    const int* edges; long long E; const float* attr;
    int bidx, nblk, din3;
    const unsigned* wp;
    if (blk < g0)           { edges = e0; E = E0; attr = at0; bidx = blk;          nblk = g0;                 din3 = 1; wp = nets; }
    else if (blk < g0 + g1) { edges = e1; E = E1; attr = at1; bidx = blk - g0;     nblk = g1;                 din3 = 1; wp = nets + NET_SLOT; }
    else                    { edges = e2; E = E2; attr = at2; bidx = blk - g0 - g1; nblk = gridDim.x - g0 - g1; din3 = 0; wp = nets + 2 * NET_SLOT; }
    const float* wpf = (const float*)wp;

    const int tid = threadIdx.x;
    const long long span = (E + nblk - 1) / nblk;
    const long long lo = (long long)bidx * span;
    const long long hi = (lo + span < E) ? (lo + span) : E;
    if (lo >= E) return;

    for (int i = tid; i < NB_MAX; i += BLK) { s_hist[i] = 0; s_rank[i] = 0; }
    __syncthreads();

    // pass A: histogram of destinations over this block's span (nt stream)
    const long long dstrow = din3 ? E : 2 * E;
    for (long long e = lo + tid; e < hi; e += BLK) {
        int d = __builtin_nontemporal_load(edges + dstrow + e);
        atomicAdd(&s_hist[d >> NPB_SHIFT], 1);
    }
    __syncthreads();

    // reserve contiguous per-bucket slots: one global int atomic per nonempty bin
    for (int i = tid; i < NB_MAX; i += BLK) {
        int h = s_hist[i];
        s_base[i] = (h > 0) ? atomicAdd(&gcount[i], h) : 0;
    }
    __syncthreads();

    // ---- pass B: software-pipelined MLP + append ----
    // raw prefetch buffers (tile t+1), consumed into packed form at loop top
    int   rdst[KPT]; bool rval[KPT];
    f32x4 rxa[KPT], rxb[KPT], rxc[KPT];
    float rat[KPT][3];

    auto load_tile = [&](long long t0) {
        #pragma unroll
        for (int u = 0; u < KPT; ++u) {
            long long e = t0 + (long long)u * BLK + tid;
            bool v = (e < hi);
            long long ee = v ? e : lo;
            rval[u] = v;
            if (din3) {
                int s = __builtin_nontemporal_load(edges + ee);
                int t = __builtin_nontemporal_load(edges + E + ee);
                rdst[u] = t;
                rxa[u] = xv[s];      // cached: keep x table L2-resident
                rxb[u] = xv[t];
            } else {
                int j = __builtin_nontemporal_load(edges + ee);
                int k = __builtin_nontemporal_load(edges + E + ee);
                int i = __builtin_nontemporal_load(edges + 2 * E + ee);
                rdst[u] = i;
                rxa[u] = xv[j];
                rxb[u] = xv[k];
                rxc[u] = xv[i];
            }
            #pragma unroll
            for (int c = 0; c < 3; ++c)
                rat[u][c] = __builtin_nontemporal_load(attr + 3 * ee + c);
        }
    };

    float b2r[9];
    #pragma unroll
    for (int i = 0; i < 9; ++i) b2r[i] = wpf[544 + i];

    load_tile(lo);   // prologue

    for (long long t0 = lo; t0 < hi; t0 += TILE) {
        // consume raw -> packed working set (waits on prefetched loads)
        unsigned dp[KPT][3];
        float    d2s[KPT];
        float    a[KPT][3];
        int      dst[KPT];
        bool     valid[KPT];
        #pragma unroll
        for (int u = 0; u < KPT; ++u) {
            valid[u] = rval[u];
            dst[u] = rdst[u];
            #pragma unroll
            for (int c = 0; c < 3; ++c) a[u][c] = rat[u][c];
            if (din3) {
                dp[u][0] = packh2(rxa[u].x - rxb[u].x, rxa[u].y - rxb[u].y);
                d2s[u]   = rxa[u].z - rxb[u].z;
                dp[u][1] = 0; dp[u][2] = 0;
            } else {
                dp[u][0] = packh2(rxb[u].x - rxa[u].x, rxb[u].y - rxa[u].y);
                dp[u][1] = packh2(rxb[u].z - rxa[u].z, rxc[u].x - rxb[u].x);
                dp[u][2] = packh2(rxc[u].y - rxb[u].y, rxc[u].z - rxb[u].z);
                d2s[u] = 0.f;
            }
        }

        // prefetch next tile while MLP computes
        if (t0 + TILE < hi) load_tile(t0 + TILE);

        float acc[KPT][9];
        #pragma unroll
        for (int u = 0; u < KPT; ++u)
            #pragma unroll
            for (int i = 0; i < 9; ++i) acc[u][i] = b2r[i];

        if (din3) {
            #pragma unroll 2
            for (int hh2 = 0; hh2 < HIDDEN / 2; ++hh2) {
                const unsigned wA = wp[2 * hh2];
                const unsigned wB = wp[2 * hh2 + 1];
                const float wcA = wpf[560 + 2 * hh2];
                const float wcB = wpf[561 + 2 * hh2];
                const float bbA = wpf[192 + 2 * hh2];
                const float bbB = wpf[193 + 2 * hh2];
                unsigned w2p[9];
                #pragma unroll
                for (int i = 0; i < 9; ++i) w2p[i] = wp[256 + hh2 * 9 + i];
                #pragma unroll
                for (int u = 0; u < KPT; ++u) {
                    float preA = fmaf(d2s[u], wcA, fdot2u(dp[u][0], wA, bbA));
                    float preB = fmaf(d2s[u], wcB, fdot2u(dp[u][0], wB, bbB));
                    unsigned h2 = packh2(fmaxf(preA, 0.f), fmaxf(preB, 0.f));
                    #pragma unroll
                    for (int i = 0; i < 9; ++i)
                        acc[u][i] = fdot2u(h2, w2p[i], acc[u][i]);
                }
            }
        } else {
            #pragma unroll 2
            for (int hh2 = 0; hh2 < HIDDEN / 2; ++hh2) {
                const unsigned wA0 = wp[(2 * hh2) * 3 + 0];
                const unsigned wA1 = wp[(2 * hh2) * 3 + 1];
                const unsigned wA2 = wp[(2 * hh2) * 3 + 2];
                const unsigned wB0 = wp[(2 * hh2 + 1) * 3 + 0];
                const unsigned wB1 = wp[(2 * hh2 + 1) * 3 + 1];
                const unsigned wB2 = wp[(2 * hh2 + 1) * 3 + 2];
                const float bbA = wpf[192 + 2 * hh2];
                const float bbB = wpf[193 + 2 * hh2];
                unsigned w2p[9];
                #pragma unroll
                for (int i = 0; i < 9; ++i) w2p[i] = wp[256 + hh2 * 9 + i];
                #pragma unroll
                for (int u = 0; u < KPT; ++u) {
                    float preA = fdot2u(dp[u][2], wA2,
                                 fdot2u(dp[u][1], wA1,
                                 fdot2u(dp[u][0], wA0, bbA)));
                    float preB = fdot2u(dp[u][2], wB2,
                                 fdot2u(dp[u][1], wB1,
                                 fdot2u(dp[u][0], wB0, bbB)));
                    unsigned h2 = packh2(fmaxf(preA, 0.f), fmaxf(preB, 0.f));
                    #pragma unroll
                    for (int i = 0; i < 9; ++i)
                        acc[u][i] = fdot2u(h2, w2p[i], acc[u][i]);
                }
            }
        }

        #pragma unroll
        for (int u = 0; u < KPT; ++u) {
            if (!valid[u]) continue;
            float y0 = fmaf(acc[u][0], a[u][0], fmaf(acc[u][1], a[u][1], acc[u][2] * a[u][2]));
            float y1 = fmaf(acc[u][3], a[u][0], fmaf(acc[u][4], a[u][1], acc[u][5] * a[u][2]));
            float y2 = fmaf(acc[u][6], a[u][0], fmaf(acc[u][7], a[u][1], acc[u][8] * a[u][2]));
            int b = dst[u] >> NPB_SHIFT;
            int r = atomicAdd(&s_rank[b], 1);            // LDS, fast
            int slot = s_base[b] + r;
            if (slot < cap) {                            // ~12-sigma safety clamp
                f32x4 rec;
                rec.x = y0; rec.y = y1; rec.z = y2;
                rec.w = __int_as_float(dst[u]);
                __builtin_nontemporal_store(
                    rec, (f32x4*)&records[(size_t)b * cap + slot]);
            }
        }
    }
}

// ---------------- Phase 2a: per-(bucket,sub) partial LDS tiles ----------------
__global__ __launch_bounds__(256) void p2_partial(
    const float4* __restrict__ records, const int* __restrict__ gcount,
    int cap, float* __restrict__ partials)
{
    __shared__ float s_acc[TILE_F];   // 6 KB
    const int b = blockIdx.x / SSPLIT;
    const int s = blockIdx.x % SSPLIT;
    const int tid = threadIdx.x;

    for (int i = tid; i < TILE_F; i += 256) s_acc[i] = 0.0f;
    __syncthreads();

    int cnt = gcount[b];
    if (cnt > cap) cnt = cap;
    const int chunk = (cnt + SSPLIT - 1) / SSPLIT;
    const int beg = s * chunk;
    const int end = min(beg + chunk, cnt);

    const f32x4* rb = (const f32x4*)(records + (size_t)b * cap);
    for (int i = beg + tid; i < end; i += 256) {
        f32x4 r = __builtin_nontemporal_load(rb + i);
        int loc = __float_as_int(r.w) - (b << NPB_SHIFT);
        atomicAdd(&s_acc[loc * 3 + 0], r.x);
        atomicAdd(&s_acc[loc * 3 + 1], r.y);
        atomicAdd(&s_acc[loc * 3 + 2], r.z);
    }
    __syncthreads();

    float* pt = partials + (size_t)blockIdx.x * TILE_F;
    for (int i = tid; i < TILE_F; i += 256) pt[i] = s_acc[i];
}

// ---------------- Phase 2b: sum SSPLIT partial tiles -> out ----------------
__global__ __launch_bounds__(256) void p2_final(
    const float4* __restrict__ partials, float4* __restrict__ out, int n4)
{
    int i4 = blockIdx.x * 256 + threadIdx.x;
    if (i4 >= n4) return;
    int b = i4 / TILE_F4;
    int loc = i4 - b * TILE_F4;
    const float4* base = partials + (size_t)b * SSPLIT * TILE_F4 + loc;
    float4 sum = base[0];
    #pragma unroll
    for (int s = 1; s < SSPLIT; ++s) {
        float4 v = base[(size_t)s * TILE_F4];
        sum.x += v.x; sum.y += v.y; sum.z += v.z; sum.w += v.w;
    }
    out[i4] = sum;
}

__global__ void p2_final_tail(const float* __restrict__ partials,
                              float* __restrict__ out, int start, int n)
{
    int idx = start + blockIdx.x * 64 + threadIdx.x;
    if (idx >= n) return;
    int b = idx / TILE_F;
    int loc = idx - b * TILE_F;
    const float* base = partials + (size_t)b * SSPLIT * TILE_F + loc;
    float sum = 0.f;
    #pragma unroll
    for (int s = 0; s < SSPLIT; ++s) sum += base[(size_t)s * TILE_F];
    out[idx] = sum;
}

// ---------------- Fallback (R1): direct device atomics, fp32 ----------------
template <int DIN, int KPT>
__global__ __launch_bounds__(256) void edge_mlp_atomic(
    const float* __restrict__ x,
    const int* __restrict__ edges, long long E,
    const float* __restrict__ attr,
    const float* __restrict__ W1, const float* __restrict__ b1,
    const float* __restrict__ W2, const float* __restrict__ b2,
    float* __restrict__ out)
{
    const int tid = threadIdx.x;
    const long long base = (long long)blockIdx.x * (blockDim.x * KPT) + tid;
    float d[KPT][DIN]; float a[KPT][3]; int dst[KPT]; bool valid[KPT];
    #pragma unroll
    for (int u = 0; u < KPT; ++u) {
        long long e = base + (long long)u * blockDim.x;
        valid[u] = (e < E);
        long long ee = valid[u] ? e : 0;
        if constexpr (DIN == 3) {
            int s = edges[ee]; int t = edges[E + ee]; dst[u] = t;
            #pragma unroll
            for (int c = 0; c < 3; ++c)
                d[u][c] = x[3 * (long long)s + c] - x[3 * (long long)t + c];
        } else {
            int j = edges[ee]; int k = edges[E + ee]; int i = edges[2 * E + ee];
            dst[u] = i;
            #pragma unroll
            for (int c = 0; c < 3; ++c) {
                float xj = x[3 * (long long)j + c];
                float xk = x[3 * (long long)k + c];
                float xi = x[3 * (long long)i + c];
                d[u][c] = xk - xj; d[u][3 + c] = xi - xk;
            }
        }
        #pragma unroll
        for (int c = 0; c < 3; ++c) a[u][c] = attr[3 * ee + c];
    }
    float acc[KPT][9];
    #pragma unroll
    for (int u = 0; u < KPT; ++u)
        #pragma unroll
        for (int i = 0; i < 9; ++i) acc[u][i] = b2[i];
    #pragma unroll 4
    for (int hh = 0; hh < HIDDEN; ++hh) {
        const float bb = b1[hh];
        float w1r[DIN];
        #pragma unroll
        for (int r = 0; r < DIN; ++r) w1r[r] = W1[r * HIDDEN + hh];
        float w2r[9];
        #pragma unroll
        for (int i = 0; i < 9; ++i) w2r[i] = W2[hh * 9 + i];
        #pragma unroll
        for (int u = 0; u < KPT; ++u) {
            float pre = bb;
            #pragma unroll
            for (int r = 0; r < DIN; ++r) pre = fmaf(d[u][r], w1r[r], pre);
            const float h = fmaxf(pre, 0.0f);
            #pragma unroll
            for (int i = 0; i < 9; ++i) acc[u][i] = fmaf(h, w2r[i], acc[u][i]);
        }
    }
    #pragma unroll
    for (int u = 0; u < KPT; ++u) {
        if (!valid[u]) continue;
        float* o = out + 3 * (long long)dst[u];
        #pragma unroll
        for (int i = 0; i < 3; ++i) {
            float y = fmaf(acc[u][3 * i + 0], a[u][0],
                      fmaf(acc[u][3 * i + 1], a[u][1],
                           acc[u][3 * i + 2] * a[u][2]));
            atomicAdd(&o[i], y);
        }
    }
}

extern "C" void kernel_launch(void* const* d_in, const int* in_sizes, int n_in,
                              void* d_out, int out_size, void* d_ws, size_t ws_size,
                              hipStream_t stream)
{
    const float* x  = (const float*)d_in[0];
    const int*   e2 = (const int*)d_in[1];
    const int*   e3 = (const int*)d_in[2];
    const int*   es = (const int*)d_in[3];
    const float* a2 = (const float*)d_in[5];
    const float* a3 = (const float*)d_in[6];
    const float* as = (const float*)d_in[7];
    const float* W1_2b = (const float*)d_in[9];
    const float* b1_2b = (const float*)d_in[10];
    const float* W2_2b = (const float*)d_in[11];
    const float* b2_2b = (const float*)d_in[12];
    const float* W1_3b = (const float*)d_in[13];
    const float* b1_3b = (const float*)d_in[14];
    const float* W2_3b = (const float*)d_in[15];
    const float* b2_3b = (const float*)d_in[16];
    const float* W1_s  = (const float*)d_in[17];
    const float* b1_s  = (const float*)d_in[18];
    const float* W2_s  = (const float*)d_in[19];
    const float* b2_s  = (const float*)d_in[20];

    const long long E2 = in_sizes[1] / 2;
    const long long E3 = in_sizes[2] / 3;
    const long long ES = in_sizes[3] / 2;
    const long long Etot = E2 + E3 + ES;
    const int n_nodes = out_size / 3;
    const int nbuckets = (n_nodes + NPB - 1) >> NPB_SHIFT;

    float* out = (float*)d_out;

    // ws layout: [gcount 1KB][nets 3*4KB][x4][partials][records]
    const size_t off_nets = 1024;
    const size_t off_x4 = off_nets + 3 * NET_SLOT * 4;
    const size_t x4_bytes = (size_t)n_nodes * sizeof(float4);
    const size_t off_part = (off_x4 + x4_bytes + 255) & ~(size_t)255;
    const size_t part_bytes = (size_t)nbuckets * SSPLIT * TILE_F * sizeof(float);
    const size_t off_rec = off_part + part_bytes;

    long long mean_per_bucket = (Etot + nbuckets - 1) / nbuckets;
    long long min_cap = mean_per_bucket + 1600;   // ~12 sigma for binomial load
    long long cap_avail =
        ((long long)ws_size - (long long)off_rec) / ((long long)nbuckets * 16);

    constexpr int SPAN = 4096;    // 8 tiles of 512 per block
    int g0 = (int)((E2 + SPAN - 1) / SPAN);
    int g1 = (int)((ES + SPAN - 1) / SPAN);
    int g2g = (int)((E3 + SPAN - 1) / SPAN);

    if (nbuckets <= NB_MAX && cap_avail >= min_cap) {
        long long capL = min_cap + 4096;
        if (capL > cap_avail) capL = cap_avail;
        int cap = (int)capL;
        int* gcount = (int*)d_ws;
        unsigned* nets = (unsigned*)((char*)d_ws + off_nets);
        float4* x4 = (float4*)((char*)d_ws + off_x4);
        float* partials = (float*)((char*)d_ws + off_part);
        float4* records = (float4*)((char*)d_ws + off_rec);

        int nb_pad = (n_nodes + 255) / 256;
        setup_kernel<<<3 + nb_pad, 256, 0, stream>>>(
            x, n_nodes, x4, gcount,
            W1_2b, b1_2b, W2_2b, b2_2b,
            W1_s,  b1_s,  W2_s,  b2_s,
            W1_3b, b1_3b, W2_3b, b2_3b,
            nets);

        p1_edge_kernel<<<g0 + g1 + g2g, 256, 0, stream>>>(
            x4,
            e2, E2, a2,
            es, ES, as,
            e3, E3, a3,
            g0, g1,
            nets, records, gcount, cap);

        p2_partial<<<nbuckets * SSPLIT, 256, 0, stream>>>(records, gcount, cap, partials);

        int n4 = out_size / 4;
        int tail = out_size - n4 * 4;
        if (n4 > 0)
            p2_final<<<(n4 + 255) / 256, 256, 0, stream>>>(
                (const float4*)partials, (float4*)out, n4);
        if (tail > 0)
            p2_final_tail<<<1, 64, 0, stream>>>(partials, out, n4 * 4, out_size);
    } else {
        // fallback: direct-atomic fp32 path (correct everywhere)
        hipMemsetAsync(out, 0, (size_t)out_size * sizeof(float), stream);
        constexpr int BLK = 256, KPT = 4;
        const long long per_blk = (long long)BLK * KPT;
        int a2g = (int)((E2 + per_blk - 1) / per_blk);
        int a3g = (int)((E3 + per_blk - 1) / per_blk);
        int asg = (int)((ES + per_blk - 1) / per_blk);
        if (a2g > 0)
            edge_mlp_atomic<3, KPT><<<a2g, BLK, 0, stream>>>(
                x, e2, E2, a2, W1_2b, b1_2b, W2_2b, b2_2b, out);
        if (a3g > 0)
            edge_mlp_atomic<6, KPT><<<a3g, BLK, 0, stream>>>(
                x, e3, E3, a3, W1_3b, b1_3b, W2_3b, b2_3b, out);
        if (asg > 0)
            edge_mlp_atomic<3, KPT><<<asg, BLK, 0, stream>>>(
                x, es, ES, as, W1_s, b1_s, W2_s, b2_s, out);
    }
}

// Round 10
// 325.343 us; speedup vs baseline: 1.3892x; 1.3892x over previous
//
#include <hip/hip_runtime.h>

// HIGNN, round 10 = R8 + LDS weight staging. R9's nt-store REVERTED
// (scattered 16B nontemporal stores bypass L2 -> partial-line HBM writes,
// WRITE_SIZE 69->156MB, p1 168->271us).
// R8 stall theory v2: MLP weight loads come from global (nets in d_ws);
// ~15 dwords/hh2-iteration, unhoistable (480 dwords > SGPR file) -> each
// iteration carries ~200cyc L2 latency vs ~100cyc VALU -> VALUBusy 32%.
// Fix: copy the 2.5KB packed net into LDS once per block; inner loop reads
// are uniform-address ds_read broadcasts (conflict-free, ~6cyc).

constexpr int HIDDEN = 64;
constexpr int NB_MAX = 256;      // LDS histogram bins (>= nbuckets)
constexpr int NPB_SHIFT = 9;     // 512 nodes per bucket
constexpr int NPB = 1 << NPB_SHIFT;
constexpr int SSPLIT = 8;        // p2 sub-blocks per bucket
constexpr int TILE_F = NPB * 3;  // floats per bucket tile (1536)
constexpr int TILE_F4 = TILE_F / 4;
constexpr int NET_SLOT = 1024;   // dwords per packed-net slot
constexpr int NET_USED = 640;    // dwords actually staged to LDS

typedef _Float16 h2_t __attribute__((ext_vector_type(2)));

__device__ __forceinline__ unsigned packh2(float a, float b) {
    auto h = __builtin_amdgcn_cvt_pkrtz(a, b);   // __fp16 ext_vector(2)
    return __builtin_bit_cast(unsigned, h);
}
__device__ __forceinline__ float fdot2u(unsigned a, unsigned b, float c) {
    h2_t ha = __builtin_bit_cast(h2_t, a);
    h2_t hb = __builtin_bit_cast(h2_t, b);
#if __has_builtin(__builtin_amdgcn_fdot2)
    return __builtin_amdgcn_fdot2(ha, hb, c, false);
#else
    return fmaf((float)ha.x, (float)hb.x, fmaf((float)ha.y, (float)hb.y, c));
#endif
}

// Packed net slot layout (dword indices within NET_SLOT):
// [0..191]   W1 packed u32. DIN3: [hh] = (W1[0][hh],W1[1][hh]).
//            DIN6: [hh*3+r] = (W1[2r][hh],W1[2r+1][hh]).
// [192..255] b1 f32
// [256..543] W2 packed u32: [256+hh2*9+i] = (W2[2hh2][i],W2[2hh2+1][i])
// [544..552] b2 f32
// [560..623] w1c f32 (DIN3 third-row weight per hh)

// ---------------- Setup: pack 3 nets + zero gcount + pad x ----------------
__global__ __launch_bounds__(256) void setup_kernel(
    const float* __restrict__ x, int n_nodes, float4* __restrict__ x4,
    int* __restrict__ gcount,
    const float* __restrict__ W1_2b, const float* __restrict__ b1_2b,
    const float* __restrict__ W2_2b, const float* __restrict__ b2_2b,
    const float* __restrict__ W1_s,  const float* __restrict__ b1_s,
    const float* __restrict__ W2_s,  const float* __restrict__ b2_s,
    const float* __restrict__ W1_3b, const float* __restrict__ b1_3b,
    const float* __restrict__ W2_3b, const float* __restrict__ b2_3b,
    unsigned* __restrict__ nets)
{
    const int blk = blockIdx.x;
    const int tid = threadIdx.x;
    if (blk < 3) {
        const float *W1, *b1, *W2, *b2; int din;
        if (blk == 0) { W1 = W1_2b; b1 = b1_2b; W2 = W2_2b; b2 = b2_2b; din = 3; }
        else if (blk == 1) { W1 = W1_s; b1 = b1_s; W2 = W2_s; b2 = b2_s; din = 3; }
        else { W1 = W1_3b; b1 = b1_3b; W2 = W2_3b; b2 = b2_3b; din = 6; }
        unsigned* slot = nets + blk * NET_SLOT;
        float* slotf = (float*)slot;
        if (tid < 64) {
            int hh = tid;
            if (din == 3) {
                slot[hh] = packh2(W1[0 * HIDDEN + hh], W1[1 * HIDDEN + hh]);
                slotf[560 + hh] = W1[2 * HIDDEN + hh];
            } else {
                #pragma unroll
                for (int r = 0; r < 3; ++r)
                    slot[hh * 3 + r] =
                        packh2(W1[(2 * r) * HIDDEN + hh], W1[(2 * r + 1) * HIDDEN + hh]);
            }
            slotf[192 + hh] = b1[hh];
        }
        for (int t = tid; t < 288; t += 256) {
            int hh2 = t / 9, i = t - hh2 * 9;
            slot[256 + t] = packh2(W2[(2 * hh2) * 9 + i], W2[(2 * hh2 + 1) * 9 + i]);
        }
        if (tid < 9) slotf[544 + tid] = b2[tid];
        if (blk == 0) gcount[tid] = 0;   // tid < 256 == NB_MAX
    } else {
        int i = (blk - 3) * 256 + tid;
        if (i < n_nodes)
            x4[i] = make_float4(x[3 * i], x[3 * i + 1], x[3 * i + 2], 0.0f);
    }
}

// ---------------- Phase 1: all 3 edge sets, MLP + bucket append ----------------
__global__ __launch_bounds__(256) void p1_edge_kernel(
    const float4* __restrict__ x4,
    const int* __restrict__ e0, long long E0, const float* __restrict__ at0,
    const int* __restrict__ e1, long long E1, const float* __restrict__ at1,
    const int* __restrict__ e2, long long E2, const float* __restrict__ at2,
    int g0, int g1,
    const unsigned* __restrict__ nets,
    float4* __restrict__ records, int* __restrict__ gcount, int cap)
{
    constexpr int BLK = 256;
    constexpr int KPT = 4;

    __shared__ int s_hist[NB_MAX];
    __shared__ int s_base[NB_MAX];
    __shared__ int s_rank[NB_MAX];
    __shared__ unsigned s_net[NET_USED];   // 2.5 KB packed weights

    // block-uniform set select (set index == net index)
    const int blk = blockIdx.x;
    const int* edges; long long E; const float* attr;
    int bidx, nblk, din3;
    const unsigned* wp;
    if (blk < g0)           { edges = e0; E = E0; attr = at0; bidx = blk;          nblk = g0;                 din3 = 1; wp = nets; }
    else if (blk < g0 + g1) { edges = e1; E = E1; attr = at1; bidx = blk - g0;     nblk = g1;                 din3 = 1; wp = nets + NET_SLOT; }
    else                    { edges = e2; E = E2; attr = at2; bidx = blk - g0 - g1; nblk = gridDim.x - g0 - g1; din3 = 0; wp = nets + 2 * NET_SLOT; }

    const int tid = threadIdx.x;
    const long long span = (E + nblk - 1) / nblk;
    const long long lo = (long long)bidx * span;
    const long long hi = (lo + span < E) ? (lo + span) : E;
    if (lo >= E) return;

    for (int i = tid; i < NB_MAX; i += BLK) { s_hist[i] = 0; s_rank[i] = 0; }
    // stage packed net into LDS (covered by the same barrier below)
    for (int i = tid; i < NET_USED; i += BLK) s_net[i] = wp[i];
    __syncthreads();

    const unsigned* w = s_net;
    const float* wf = (const float*)s_net;

    // pass A: histogram of destinations over this block's span
    const long long dstrow = din3 ? E : 2 * E;
    for (long long e = lo + tid; e < hi; e += BLK) {
        int d = edges[dstrow + e];
        atomicAdd(&s_hist[d >> NPB_SHIFT], 1);
    }
    __syncthreads();

    // reserve contiguous per-bucket slots: one global int atomic per nonempty bin
    for (int i = tid; i < NB_MAX; i += BLK) {
        int h = s_hist[i];
        s_base[i] = (h > 0) ? atomicAdd(&gcount[i], h) : 0;
    }
    __syncthreads();

    // pass B: MLP + append, tiles of 1024 edges (4/thread)
    for (long long t0 = lo; t0 < hi; t0 += BLK * KPT) {
        unsigned dp[KPT][3];    // packed fp16 input pairs
        float    d2s[KPT];      // DIN3 third component (fp32)
        float    a[KPT][3];
        int      dst[KPT];
        bool     valid[KPT];

        #pragma unroll
        for (int u = 0; u < KPT; ++u) {
            long long e = t0 + (long long)u * BLK + tid;
            valid[u] = (e < hi);
            long long ee = valid[u] ? e : lo;
            if (din3) {
                int s = edges[ee];
                int t = edges[E + ee];
                dst[u] = t;
                float4 xs = x4[s];
                float4 xt = x4[t];
                dp[u][0] = packh2(xs.x - xt.x, xs.y - xt.y);
                d2s[u]   = xs.z - xt.z;
                dp[u][1] = 0; dp[u][2] = 0;
            } else {
                int j = edges[ee];
                int k = edges[E + ee];
                int i = edges[2 * E + ee];
                dst[u] = i;
                float4 xj = x4[j];
                float4 xk = x4[k];
                float4 xi = x4[i];
                dp[u][0] = packh2(xk.x - xj.x, xk.y - xj.y);
                dp[u][1] = packh2(xk.z - xj.z, xi.x - xk.x);
                dp[u][2] = packh2(xi.y - xk.y, xi.z - xk.z);
                d2s[u] = 0.f;
            }
            #pragma unroll
            for (int c = 0; c < 3; ++c) a[u][c] = attr[3 * ee + c];
        }

        float acc[KPT][9];
        #pragma unroll
        for (int u = 0; u < KPT; ++u)
            #pragma unroll
            for (int i = 0; i < 9; ++i) acc[u][i] = wf[544 + i];  // b2

        if (din3) {
            #pragma unroll 2
            for (int hh2 = 0; hh2 < HIDDEN / 2; ++hh2) {
                const unsigned wA = w[2 * hh2];
                const unsigned wB = w[2 * hh2 + 1];
                const float wcA = wf[560 + 2 * hh2];
                const float wcB = wf[561 + 2 * hh2];
                const float bbA = wf[192 + 2 * hh2];
                const float bbB = wf[193 + 2 * hh2];
                unsigned w2p[9];
                #pragma unroll
                for (int i = 0; i < 9; ++i) w2p[i] = w[256 + hh2 * 9 + i];
                #pragma unroll
                for (int u = 0; u < KPT; ++u) {
                    float preA = fmaf(d2s[u], wcA, fdot2u(dp[u][0], wA, bbA));
                    float preB = fmaf(d2s[u], wcB, fdot2u(dp[u][0], wB, bbB));
                    unsigned h2 = packh2(fmaxf(preA, 0.f), fmaxf(preB, 0.f));
                    #pragma unroll
                    for (int i = 0; i < 9; ++i)
                        acc[u][i] = fdot2u(h2, w2p[i], acc[u][i]);
                }
            }
        } else {
            #pragma unroll 2
            for (int hh2 = 0; hh2 < HIDDEN / 2; ++hh2) {
                const unsigned wA0 = w[(2 * hh2) * 3 + 0];
                const unsigned wA1 = w[(2 * hh2) * 3 + 1];
                const unsigned wA2 = w[(2 * hh2) * 3 + 2];
                const unsigned wB0 = w[(2 * hh2 + 1) * 3 + 0];
                const unsigned wB1 = w[(2 * hh2 + 1) * 3 + 1];
                const unsigned wB2 = w[(2 * hh2 + 1) * 3 + 2];
                const float bbA = wf[192 + 2 * hh2];
                const float bbB = wf[193 + 2 * hh2];
                unsigned w2p[9];
                #pragma unroll
                for (int i = 0; i < 9; ++i) w2p[i] = w[256 + hh2 * 9 + i];
                #pragma unroll
                for (int u = 0; u < KPT; ++u) {
                    float preA = fdot2u(dp[u][2], wA2,
                                 fdot2u(dp[u][1], wA1,
                                 fdot2u(dp[u][0], wA0, bbA)));
                    float preB = fdot2u(dp[u][2], wB2,
                                 fdot2u(dp[u][1], wB1,
                                 fdot2u(dp[u][0], wB0, bbB)));
                    unsigned h2 = packh2(fmaxf(preA, 0.f), fmaxf(preB, 0.f));
                    #pragma unroll
                    for (int i = 0; i < 9; ++i)
                        acc[u][i] = fdot2u(h2, w2p[i], acc[u][i]);
                }
            }
        }

        #pragma unroll
        for (int u = 0; u < KPT; ++u) {
            if (!valid[u]) continue;
            float y0 = fmaf(acc[u][0], a[u][0], fmaf(acc[u][1], a[u][1], acc[u][2] * a[u][2]));
            float y1 = fmaf(acc[u][3], a[u][0], fmaf(acc[u][4], a[u][1], acc[u][5] * a[u][2]));
            float y2 = fmaf(acc[u][6], a[u][0], fmaf(acc[u][7], a[u][1], acc[u][8] * a[u][2]));
            int b = dst[u] >> NPB_SHIFT;
            int r = atomicAdd(&s_rank[b], 1);            // LDS, fast
            int slot = s_base[b] + r;
            if (slot < cap)                              // ~12-sigma safety clamp
                records[(size_t)b * cap + slot] =
                    make_float4(y0, y1, y2, __int_as_float(dst[u]));
        }
    }
}

// ---------------- Phase 2a: per-(bucket,sub) partial LDS tiles ----------------
__global__ __launch_bounds__(256) void p2_partial(
    const float4* __restrict__ records, const int* __restrict__ gcount,
    int cap, float* __restrict__ partials)
{
    __shared__ float s_acc[TILE_F];   // 6 KB
    const int b = blockIdx.x / SSPLIT;
    const int s = blockIdx.x % SSPLIT;
    const int tid = threadIdx.x;

    for (int i = tid; i < TILE_F; i += 256) s_acc[i] = 0.0f;
    __syncthreads();

    int cnt = gcount[b];
    if (cnt > cap) cnt = cap;
    const int chunk = (cnt + SSPLIT - 1) / SSPLIT;
    const int beg = s * chunk;
    const int end = min(beg + chunk, cnt);

    const float4* rb = records + (size_t)b * cap;
    for (int i = beg + tid; i < end; i += 256) {
        float4 r = rb[i];
        int loc = __float_as_int(r.w) - (b << NPB_SHIFT);
        atomicAdd(&s_acc[loc * 3 + 0], r.x);
        atomicAdd(&s_acc[loc * 3 + 1], r.y);
        atomicAdd(&s_acc[loc * 3 + 2], r.z);
    }
    __syncthreads();

    float* pt = partials + (size_t)blockIdx.x * TILE_F;
    for (int i = tid; i < TILE_F; i += 256) pt[i] = s_acc[i];
}

// ---------------- Phase 2b: sum SSPLIT partial tiles -> out ----------------
__global__ __launch_bounds__(256) void p2_final(
    const float4* __restrict__ partials, float4* __restrict__ out, int n4)
{
    int i4 = blockIdx.x * 256 + threadIdx.x;
    if (i4 >= n4) return;
    int b = i4 / TILE_F4;
    int loc = i4 - b * TILE_F4;
    const float4* base = partials + (size_t)b * SSPLIT * TILE_F4 + loc;
    float4 sum = base[0];
    #pragma unroll
    for (int s = 1; s < SSPLIT; ++s) {
        float4 v = base[(size_t)s * TILE_F4];
        sum.x += v.x; sum.y += v.y; sum.z += v.z; sum.w += v.w;
    }
    out[i4] = sum;
}

__global__ void p2_final_tail(const float* __restrict__ partials,
                              float* __restrict__ out, int start, int n)
{
    int idx = start + blockIdx.x * 64 + threadIdx.x;
    if (idx >= n) return;
    int b = idx / TILE_F;
    int loc = idx - b * TILE_F;
    const float* base = partials + (size_t)b * SSPLIT * TILE_F + loc;
    float sum = 0.f;
    #pragma unroll
    for (int s = 0; s < SSPLIT; ++s) sum += base[(size_t)s * TILE_F];
    out[idx] = sum;
}

// ---------------- Fallback (R1): direct device atomics, fp32 ----------------
template <int DIN, int KPT>
__global__ __launch_bounds__(256) void edge_mlp_atomic(
    const float* __restrict__ x,
    const int* __restrict__ edges, long long E,
    const float* __restrict__ attr,
    const float* __restrict__ W1, const float* __restrict__ b1,
    const float* __restrict__ W2, const float* __restrict__ b2,
    float* __restrict__ out)
{
    const int tid = threadIdx.x;
    const long long base = (long long)blockIdx.x * (blockDim.x * KPT) + tid;
    float d[KPT][DIN]; float a[KPT][3]; int dst[KPT]; bool valid[KPT];
    #pragma unroll
    for (int u = 0; u < KPT; ++u) {
        long long e = base + (long long)u * blockDim.x;
        valid[u] = (e < E);
        long long ee = valid[u] ? e : 0;
        if constexpr (DIN == 3) {
            int s = edges[ee]; int t = edges[E + ee]; dst[u] = t;
            #pragma unroll
            for (int c = 0; c < 3; ++c)
                d[u][c] = x[3 * (long long)s + c] - x[3 * (long long)t + c];
        } else {
            int j = edges[ee]; int k = edges[E + ee]; int i = edges[2 * E + ee];
            dst[u] = i;
            #pragma unroll
            for (int c = 0; c < 3; ++c) {
                float xj = x[3 * (long long)j + c];
                float xk = x[3 * (long long)k + c];
                float xi = x[3 * (long long)i + c];
                d[u][c] = xk - xj; d[u][3 + c] = xi - xk;
            }
        }
        #pragma unroll
        for (int c = 0; c < 3; ++c) a[u][c] = attr[3 * ee + c];
    }
    float acc[KPT][9];
    #pragma unroll
    for (int u = 0; u < KPT; ++u)
        #pragma unroll
        for (int i = 0; i < 9; ++i) acc[u][i] = b2[i];
    #pragma unroll 4
    for (int hh = 0; hh < HIDDEN; ++hh) {
        const float bb = b1[hh];
        float w1r[DIN];
        #pragma unroll
        for (int r = 0; r < DIN; ++r) w1r[r] = W1[r * HIDDEN + hh];
        float w2r[9];
        #pragma unroll
        for (int i = 0; i < 9; ++i) w2r[i] = W2[hh * 9 + i];
        #pragma unroll
        for (int u = 0; u < KPT; ++u) {
            float pre = bb;
            #pragma unroll
            for (int r = 0; r < DIN; ++r) pre = fmaf(d[u][r], w1r[r], pre);
            const float h = fmaxf(pre, 0.0f);
            #pragma unroll
            for (int i = 0; i < 9; ++i) acc[u][i] = fmaf(h, w2r[i], acc[u][i]);
        }
    }
    #pragma unroll
    for (int u = 0; u < KPT; ++u) {
        if (!valid[u]) continue;
        float* o = out + 3 * (long long)dst[u];
        #pragma unroll
        for (int i = 0; i < 3; ++i) {
            float y = fmaf(acc[u][3 * i + 0], a[u][0],
                      fmaf(acc[u][3 * i + 1], a[u][1],
                           acc[u][3 * i + 2] * a[u][2]));
            atomicAdd(&o[i], y);
        }
    }
}

extern "C" void kernel_launch(void* const* d_in, const int* in_sizes, int n_in,
                              void* d_out, int out_size, void* d_ws, size_t ws_size,
                              hipStream_t stream)
{
    const float* x  = (const float*)d_in[0];
    const int*   e2 = (const int*)d_in[1];
    const int*   e3 = (const int*)d_in[2];
    const int*   es = (const int*)d_in[3];
    const float* a2 = (const float*)d_in[5];
    const float* a3 = (const float*)d_in[6];
    const float* as = (const float*)d_in[7];
    const float* W1_2b = (const float*)d_in[9];
    const float* b1_2b = (const float*)d_in[10];
    const float* W2_2b = (const float*)d_in[11];
    const float* b2_2b = (const float*)d_in[12];
    const float* W1_3b = (const float*)d_in[13];
    const float* b1_3b = (const float*)d_in[14];
    const float* W2_3b = (const float*)d_in[15];
    const float* b2_3b = (const float*)d_in[16];
    const float* W1_s  = (const float*)d_in[17];
    const float* b1_s  = (const float*)d_in[18];
    const float* W2_s  = (const float*)d_in[19];
    const float* b2_s  = (const float*)d_in[20];

    const long long E2 = in_sizes[1] / 2;
    const long long E3 = in_sizes[2] / 3;
    const long long ES = in_sizes[3] / 2;
    const long long Etot = E2 + E3 + ES;
    const int n_nodes = out_size / 3;
    const int nbuckets = (n_nodes + NPB - 1) >> NPB_SHIFT;

    float* out = (float*)d_out;

    // ws layout: [gcount 1KB][nets 3*4KB][x4][partials][records]
    const size_t off_nets = 1024;
    const size_t off_x4 = off_nets + 3 * NET_SLOT * 4;
    const size_t x4_bytes = (size_t)n_nodes * sizeof(float4);
    const size_t off_part = (off_x4 + x4_bytes + 255) & ~(size_t)255;
    const size_t part_bytes = (size_t)nbuckets * SSPLIT * TILE_F * sizeof(float);
    const size_t off_rec = off_part + part_bytes;

    long long mean_per_bucket = (Etot + nbuckets - 1) / nbuckets;
    long long min_cap = mean_per_bucket + 1600;   // ~12 sigma for binomial load
    long long cap_avail =
        ((long long)ws_size - (long long)off_rec) / ((long long)nbuckets * 16);

    constexpr int SPAN = 2048;    // 2 tiles of 1024 per block
    int g0 = (int)((E2 + SPAN - 1) / SPAN);
    int g1 = (int)((ES + SPAN - 1) / SPAN);
    int g2g = (int)((E3 + SPAN - 1) / SPAN);

    if (nbuckets <= NB_MAX && cap_avail >= min_cap) {
        long long capL = min_cap + 4096;
        if (capL > cap_avail) capL = cap_avail;
        int cap = (int)capL;
        int* gcount = (int*)d_ws;
        unsigned* nets = (unsigned*)((char*)d_ws + off_nets);
        float4* x4 = (float4*)((char*)d_ws + off_x4);
        float* partials = (float*)((char*)d_ws + off_part);
        float4* records = (float4*)((char*)d_ws + off_rec);

        int nb_pad = (n_nodes + 255) / 256;
        setup_kernel<<<3 + nb_pad, 256, 0, stream>>>(
            x, n_nodes, x4, gcount,
            W1_2b, b1_2b, W2_2b, b2_2b,
            W1_s,  b1_s,  W2_s,  b2_s,
            W1_3b, b1_3b, W2_3b, b2_3b,
            nets);

        p1_edge_kernel<<<g0 + g1 + g2g, 256, 0, stream>>>(
            x4,
            e2, E2, a2,
            es, ES, as,
            e3, E3, a3,
            g0, g1,
            nets, records, gcount, cap);

        p2_partial<<<nbuckets * SSPLIT, 256, 0, stream>>>(records, gcount, cap, partials);

        int n4 = out_size / 4;
        int tail = out_size - n4 * 4;
        if (n4 > 0)
            p2_final<<<(n4 + 255) / 256, 256, 0, stream>>>(
                (const float4*)partials, (float4*)out, n4);
        if (tail > 0)
            p2_final_tail<<<1, 64, 0, stream>>>(partials, out, n4 * 4, out_size);
    } else {
        // fallback: direct-atomic fp32 path (correct everywhere)
        hipMemsetAsync(out, 0, (size_t)out_size * sizeof(float), stream);
        constexpr int BLK = 256, KPT = 4;
        const long long per_blk = (long long)BLK * KPT;
        int a2g = (int)((E2 + per_blk - 1) / per_blk);
        int a3g = (int)((E3 + per_blk - 1) / per_blk);
        int asg = (int)((ES + per_blk - 1) / per_blk);
        if (a2g > 0)
            edge_mlp_atomic<3, KPT><<<a2g, BLK, 0, stream>>>(
                x, e2, E2, a2, W1_2b, b1_2b, W2_2b, b2_2b, out);
        if (a3g > 0)
            edge_mlp_atomic<6, KPT><<<a3g, BLK, 0, stream>>>(
                x, e3, E3, a3, W1_3b, b1_3b, W2_3b, b2_3b, out);
        if (asg > 0)
            edge_mlp_atomic<3, KPT><<<asg, BLK, 0, stream>>>(
                x, es, ES, as, W1_s, b1_s, W2_s, b2_s, out);
    }
}